// Round 4
// baseline (1857.588 us; speedup 1.0000x reference)
//
#include <hip/hip_runtime.h>
#include <stdint.h>

#define N_NODES 65536
#define N_EDGES (N_NODES * 16)
#define EMB 128
#define G_GRAPHS 512
#define NPG 128
#define ITERS 8

#define RNG_MODE 0

typedef __attribute__((ext_vector_type(8))) short short8v;
typedef __attribute__((ext_vector_type(4))) float f32x4;

#define MFMA16(a, b, c) __builtin_amdgcn_mfma_f32_16x16x32_bf16((a), (b), (c), 0, 0, 0)

__host__ __device__ __forceinline__ uint32_t rotl32(uint32_t v, int r) {
    return (v << r) | (v >> (32 - r));
}

// JAX threefry2x32, 20 rounds, exact key schedule
__host__ __device__ __forceinline__ void tf2x32(uint32_t k0, uint32_t k1,
                                                uint32_t x0, uint32_t x1,
                                                uint32_t& o0, uint32_t& o1) {
    uint32_t ks2 = k0 ^ k1 ^ 0x1BD11BDAu;
    x0 += k0; x1 += k1;
#define TF_R(r) { x0 += x1; x1 = rotl32(x1, (r)); x1 ^= x0; }
    TF_R(13) TF_R(15) TF_R(26) TF_R(6)
    x0 += k1;  x1 += ks2 + 1u;
    TF_R(17) TF_R(29) TF_R(16) TF_R(24)
    x0 += ks2; x1 += k0 + 2u;
    TF_R(13) TF_R(15) TF_R(26) TF_R(6)
    x0 += k0;  x1 += k1 + 3u;
    TF_R(17) TF_R(29) TF_R(16) TF_R(24)
    x0 += k1;  x1 += ks2 + 4u;
    TF_R(13) TF_R(15) TF_R(26) TF_R(6)
    x0 += ks2; x1 += k0 + 5u;
#undef TF_R
    o0 = x0; o1 = x1;
}

__device__ __forceinline__ uint32_t draw_bits32(uint32_t k0, uint32_t k1,
                                                uint32_t idx, uint32_t total) {
#if RNG_MODE == 0
    uint32_t a, b;
    tf2x32(k0, k1, 0u, idx, a, b);
    return a ^ b;
#else
    uint32_t half = total >> 1;
    uint32_t a, b;
    if (idx < half) { tf2x32(k0, k1, idx, idx + half, a, b); return a; }
    else            { tf2x32(k0, k1, idx - half, idx, a, b); return b; }
#endif
}

__device__ __forceinline__ float bits_to_unit(uint32_t bits) {
    return __uint_as_float((bits >> 9) | 0x3f800000u) - 1.0f;
}

__device__ __forceinline__ float lrelu(float v) { return v >= 0.0f ? v : 0.01f * v; }

// fp32 -> bf16 RNE
__device__ __forceinline__ ushort f2bf(float f) {
    uint32_t u = __float_as_uint(f);
    u = u + 0x7fffu + ((u >> 16) & 1u);
    return (ushort)(u >> 16);
}
__device__ __forceinline__ float bf2f(ushort h) {
    return __uint_as_float(((uint32_t)h) << 16);
}
__device__ __forceinline__ void split3(float a, ushort& h, ushort& m, ushort& l) {
    h = f2bf(a); float r = a - bf2f(h);
    m = f2bf(r); r = r - bf2f(m);
    l = f2bf(r);
}

// ---------------- CSR build ----------------

__global__ void k_deg(const int* __restrict__ ei, int* __restrict__ deg) {
    int e = blockIdx.x * 256 + threadIdx.x;
    if (e < N_EDGES) atomicAdd(&deg[ei[N_EDGES + e]], 1);
}

__global__ __launch_bounds__(1024) void k_scan(const int* __restrict__ deg,
                                               int* __restrict__ indptr,
                                               int* __restrict__ cursor) {
    __shared__ int part[1024];
    int t = threadIdx.x;
    int base = t * 64;
    int s = 0;
    for (int i = 0; i < 64; ++i) s += deg[base + i];
    part[t] = s;
    __syncthreads();
    for (int off = 1; off < 1024; off <<= 1) {
        int v = (t >= off) ? part[t - off] : 0;
        __syncthreads();
        part[t] += v;
        __syncthreads();
    }
    int run = (t == 0) ? 0 : part[t - 1];
    for (int i = 0; i < 64; ++i) {
        int idx = base + i;
        indptr[idx] = run;
        cursor[idx] = run;
        run += deg[idx];
    }
    if (t == 1023) indptr[N_NODES] = run;
}

__global__ void k_scatter(const int* __restrict__ ei, int* __restrict__ cursor,
                          int* __restrict__ eid) {
    int e = blockIdx.x * 256 + threadIdx.x;
    if (e < N_EDGES) {
        int d = ei[N_EDGES + e];
        int pos = atomicAdd(&cursor[d], 1);
        eid[pos] = e;
    }
}

// wave-parallel bitonic sort of each node's edge-id segment (ascending).
// one 64-lane wave per node; INT_MAX padding; serial fallback for deg>64.
__global__ __launch_bounds__(256) void k_sortw(const int* __restrict__ indptr,
                                               int* __restrict__ eid) {
    int node = blockIdx.x * 4 + (threadIdx.x >> 6);
    int lane = threadIdx.x & 63;
    int b = indptr[node], e = indptr[node + 1];
    int deg = e - b;
    if (deg <= 1) return;
    if (deg > 64) {
        if (lane == 0) {
            for (int p = b + 1; p < e; ++p) {
                int v = eid[p];
                int q = p - 1;
                while (q >= b && eid[q] > v) { eid[q + 1] = eid[q]; --q; }
                eid[q + 1] = v;
            }
        }
        return;
    }
    int v = (lane < deg) ? eid[b + lane] : 0x7fffffff;
#pragma unroll
    for (int k = 2; k <= 64; k <<= 1) {
#pragma unroll
        for (int j = k >> 1; j > 0; j >>= 1) {
            int other = __shfl_xor(v, j);
            int partner = lane ^ j;
            bool up = ((lane & k) == 0);
            bool keepMin = ((lane < partner) == up);
            int mn = min(v, other), mx = max(v, other);
            v = keepMin ? mn : mx;
        }
    }
    if (lane < deg) eid[b + lane] = v;
}

__global__ void k_gather(const int* __restrict__ eid, const int* __restrict__ ei,
                         const float* __restrict__ ea, int* __restrict__ srcs,
                         float2* __restrict__ att) {
    int p = blockIdx.x * 256 + threadIdx.x;
    if (p >= N_EDGES) return;
    int e = eid[p];
    srcs[p] = ei[e];
    att[p] = *reinterpret_cast<const float2*>(ea + 2 * (size_t)e);
}

// ---------------- weight pre-split ----------------
// Wp layout (bf16/ushort): idx = (((mat*4 + kb)*3 + lev)*128 + col)*32 + kk
// mats: 0=Ws, 1=Wd, 2=Wux, 3=Wum
__global__ void k_split_w(const float* __restrict__ W0, const float* __restrict__ W1,
                          const float* __restrict__ W2, const float* __restrict__ W3,
                          ushort* __restrict__ Wp) {
    int tid = blockIdx.x * 256 + threadIdx.x;
    int mat = tid >> 14;
    int rem = tid & 16383;
    int k = rem >> 7, col = rem & 127;
    const float* W = (mat == 0) ? W0 : (mat == 1) ? W1 : (mat == 2) ? W2 : W3;
    float w = W[k * 128 + col];
    ushort h, m, l;
    split3(w, h, m, l);
    int kb = k >> 5, kk = k & 31;
    size_t base = (((size_t)(mat * 4 + kb) * 3) * 128 + col) * 32 + kk;
    Wp[base] = h;
    Wp[base + 4096] = m;
    Wp[base + 8192] = l;
}

// ---------------- network ----------------

__global__ void k_embed(const float* __restrict__ nf, const float* __restrict__ We,
                        const float* __restrict__ be, float* __restrict__ x) {
    int idx = blockIdx.x * 256 + threadIdx.x;
    int n = idx >> 7, j = idx & 127;
    float acc = be[j];
#pragma unroll
    for (int f = 0; f < 5; ++f) acc += nf[n * 5 + f] * We[f * EMB + j];
    x[idx] = lrelu(acc);
}

__global__ __launch_bounds__(128) void k_pool0(const float* __restrict__ x,
                                               float* __restrict__ g, float* __restrict__ gu,
                                               const float* __restrict__ Wug) {
    __shared__ float pl[128];
    int gid = blockIdx.x, j = threadIdx.x;
    const float* xb = x + (size_t)gid * NPG * EMB;
    float s = 0.f;
    for (int n = 0; n < NPG; ++n) s += xb[n * EMB + j];
    s *= (1.0f / NPG);
    g[gid * EMB + j] = s;
    pl[j] = s;
    __syncthreads();
    float acc = 0.f;
    for (int k = 0; k < EMB; ++k) acc += pl[k] * Wug[k * EMB + j];
    gu[gid * EMB + j] = acc;
}

// MFMA split-bf16 projections: xs = x@Ws, xd = x@Wd + bm
__global__ __launch_bounds__(256, 2) void k_gemmP(const float* __restrict__ x,
                                                  const ushort* __restrict__ Wp,
                                                  const float* __restrict__ bm,
                                                  float* __restrict__ xs,
                                                  float* __restrict__ xd) {
    int wid = threadIdx.x >> 6, lane = threadIdx.x & 63;
    int rowq = lane & 15, half = lane >> 4;
    int wrow = blockIdx.x * 128 + wid * 32;
    int laneoff = rowq * 32 + half * 8;

    for (int mat = 0; mat < 2; ++mat) {
        f32x4 acc[2][8];
#pragma unroll
        for (int rt = 0; rt < 2; ++rt)
#pragma unroll
            for (int ct = 0; ct < 8; ++ct) acc[rt][ct] = (f32x4){0.f, 0.f, 0.f, 0.f};
        for (int kb = 0; kb < 4; ++kb) {
            short8v Ah[2], Am[2], Al[2];
#pragma unroll
            for (int rt = 0; rt < 2; ++rt) {
                const float* ap = x + (size_t)(wrow + rt * 16 + rowq) * 128 + kb * 32 + half * 8;
                float4 a0 = *reinterpret_cast<const float4*>(ap);
                float4 a1 = *reinterpret_cast<const float4*>(ap + 4);
                float av[8] = {a0.x, a0.y, a0.z, a0.w, a1.x, a1.y, a1.z, a1.w};
#pragma unroll
                for (int j = 0; j < 8; ++j) {
                    ushort h, m, l;
                    split3(av[j], h, m, l);
                    Ah[rt][j] = (short)h; Am[rt][j] = (short)m; Al[rt][j] = (short)l;
                }
            }
            const ushort* b0 = Wp + (size_t)(mat * 4 + kb) * 3 * 4096 + laneoff;
#pragma unroll
            for (int ct = 0; ct < 8; ++ct) {
                short8v Bh = *reinterpret_cast<const short8v*>(b0 + ct * 512);
                short8v Bm = *reinterpret_cast<const short8v*>(b0 + 4096 + ct * 512);
                short8v Bl = *reinterpret_cast<const short8v*>(b0 + 8192 + ct * 512);
#pragma unroll
                for (int rt = 0; rt < 2; ++rt) {
                    acc[rt][ct] = MFMA16(Ah[rt], Bh, acc[rt][ct]);
                    acc[rt][ct] = MFMA16(Ah[rt], Bm, acc[rt][ct]);
                    acc[rt][ct] = MFMA16(Am[rt], Bh, acc[rt][ct]);
                    acc[rt][ct] = MFMA16(Ah[rt], Bl, acc[rt][ct]);
                    acc[rt][ct] = MFMA16(Al[rt], Bh, acc[rt][ct]);
                    acc[rt][ct] = MFMA16(Am[rt], Bm, acc[rt][ct]);
                }
            }
        }
        float* out = (mat == 0) ? xs : xd;
#pragma unroll
        for (int ct = 0; ct < 8; ++ct) {
            int col = ct * 16 + rowq;
            float badd = (mat == 1) ? bm[col] : 0.f;
#pragma unroll
            for (int rt = 0; rt < 2; ++rt) {
#pragma unroll
                for (int j = 0; j < 4; ++j) {
                    int row = wrow + rt * 16 + half * 4 + j;
                    out[(size_t)row * 128 + col] = acc[rt][ct][j] + badd;
                }
            }
        }
    }
}

// per-dst aggregation, float2/lane, 16-deep clamp-batched gather (order-exact)
__global__ __launch_bounds__(256) void k_edge(const float* __restrict__ xs,
                                              const float* __restrict__ xd,
                                              float* __restrict__ agg,
                                              const int* __restrict__ indptr,
                                              const int* __restrict__ srcs,
                                              const float2* __restrict__ att,
                                              const float* __restrict__ Wme) {
    int node = blockIdx.x * 4 + threadIdx.y;
    int j = threadIdx.x;
    const float2* xs2 = reinterpret_cast<const float2*>(xs);
    float2 w0 = reinterpret_cast<const float2*>(Wme)[j];
    float2 w1 = reinterpret_cast<const float2*>(Wme + EMB)[j];
    float2 bv = reinterpret_cast<const float2*>(xd)[node * 64 + j];
    float bx = bv.x, by = bv.y;
    int b = indptr[node], e = indptr[node + 1];
    float ax = 0.f, ay = 0.f;
    for (int p = b; p < e; p += 16) {
        int s[16]; float2 a[16]; float2 v[16];
#pragma unroll
        for (int i = 0; i < 16; ++i) {
            int q = p + i; q = (q < e) ? q : (e - 1);
            s[i] = srcs[q];
        }
#pragma unroll
        for (int i = 0; i < 16; ++i) {
            int q = p + i; q = (q < e) ? q : (e - 1);
            a[i] = att[q];
        }
#pragma unroll
        for (int i = 0; i < 16; ++i) v[i] = xs2[s[i] * 64 + j];
#pragma unroll
        for (int i = 0; i < 16; ++i) {
            float tx = v[i].x + bx + a[i].x * w0.x + a[i].y * w1.x;
            float ty = v[i].y + by + a[i].x * w0.y + a[i].y * w1.y;
            bool valid = (p + i) < e;
            ax += valid ? lrelu(tx) : 0.f;
            ay += valid ? lrelu(ty) : 0.f;
        }
    }
    reinterpret_cast<float2*>(agg)[node * 64 + j] = make_float2(ax, ay);
}

// x = lrelu(x@Wux + agg@Wum + gu + bu) via split-bf16 MFMA, fused global update
__global__ __launch_bounds__(256, 2) void k_upd(const float* __restrict__ x_in,
                                                const float* __restrict__ agg,
                                                const ushort* __restrict__ Wp,
                                                const float* __restrict__ bu,
                                                float* __restrict__ x,
                                                float* __restrict__ g,
                                                float* __restrict__ gu,
                                                const float* __restrict__ Wgg,
                                                const float* __restrict__ Wgp,
                                                const float* __restrict__ bg,
                                                const float* __restrict__ Wug) {
    __shared__ float pl[4][128];
    __shared__ float pooled_s[128];
    __shared__ float go_s[128];
    __shared__ float gn_s[128];
    int wid = threadIdx.x >> 6, lane = threadIdx.x & 63;
    int rowq = lane & 15, half = lane >> 4;
    int gid = blockIdx.x;
    int wrow = gid * 128 + wid * 32;
    int laneoff = rowq * 32 + half * 8;

    f32x4 acc[2][8];
#pragma unroll
    for (int rt = 0; rt < 2; ++rt)
#pragma unroll
        for (int ct = 0; ct < 8; ++ct) acc[rt][ct] = (f32x4){0.f, 0.f, 0.f, 0.f};

    for (int srci = 0; srci < 2; ++srci) {
        const float* A = (srci == 0) ? x_in : agg;
        int mat = 2 + srci;
        for (int kb = 0; kb < 4; ++kb) {
            short8v Ah[2], Am[2], Al[2];
#pragma unroll
            for (int rt = 0; rt < 2; ++rt) {
                const float* ap = A + (size_t)(wrow + rt * 16 + rowq) * 128 + kb * 32 + half * 8;
                float4 a0 = *reinterpret_cast<const float4*>(ap);
                float4 a1 = *reinterpret_cast<const float4*>(ap + 4);
                float av[8] = {a0.x, a0.y, a0.z, a0.w, a1.x, a1.y, a1.z, a1.w};
#pragma unroll
                for (int j = 0; j < 8; ++j) {
                    ushort h, m, l;
                    split3(av[j], h, m, l);
                    Ah[rt][j] = (short)h; Am[rt][j] = (short)m; Al[rt][j] = (short)l;
                }
            }
            const ushort* b0 = Wp + (size_t)(mat * 4 + kb) * 3 * 4096 + laneoff;
#pragma unroll
            for (int ct = 0; ct < 8; ++ct) {
                short8v Bh = *reinterpret_cast<const short8v*>(b0 + ct * 512);
                short8v Bm = *reinterpret_cast<const short8v*>(b0 + 4096 + ct * 512);
                short8v Bl = *reinterpret_cast<const short8v*>(b0 + 8192 + ct * 512);
#pragma unroll
                for (int rt = 0; rt < 2; ++rt) {
                    acc[rt][ct] = MFMA16(Ah[rt], Bh, acc[rt][ct]);
                    acc[rt][ct] = MFMA16(Ah[rt], Bm, acc[rt][ct]);
                    acc[rt][ct] = MFMA16(Am[rt], Bh, acc[rt][ct]);
                    acc[rt][ct] = MFMA16(Ah[rt], Bl, acc[rt][ct]);
                    acc[rt][ct] = MFMA16(Al[rt], Bh, acc[rt][ct]);
                    acc[rt][ct] = MFMA16(Am[rt], Bm, acc[rt][ct]);
                }
            }
        }
    }

#pragma unroll
    for (int ct = 0; ct < 8; ++ct) {
        int col = ct * 16 + rowq;
        float guv = gu[gid * 128 + col];
        float buv = bu[col];
        float csum = 0.f;
#pragma unroll
        for (int rt = 0; rt < 2; ++rt) {
#pragma unroll
            for (int j = 0; j < 4; ++j) {
                int row = wrow + rt * 16 + half * 4 + j;
                float o = lrelu(acc[rt][ct][j] + guv + buv);
                x[(size_t)row * 128 + col] = o;
                csum += o;
            }
        }
        csum += __shfl_down(csum, 32);
        csum += __shfl_down(csum, 16);
        if (half == 0) pl[wid][col] = csum;
    }
    __syncthreads();
    int t = threadIdx.x;
    if (t < 128) {
        pooled_s[t] = (pl[0][t] + pl[1][t] + pl[2][t] + pl[3][t]) * (1.0f / NPG);
        go_s[t] = g[gid * 128 + t];
    }
    __syncthreads();
    if (t < 128) {
        float accg = bg[t];
        for (int k = 0; k < 128; ++k) accg += go_s[k] * Wgg[k * 128 + t];
        for (int k = 0; k < 128; ++k) accg += pooled_s[k] * Wgp[k * 128 + t];
        float gnew = lrelu(accg);
        g[gid * 128 + t] = gnew;
        gn_s[t] = gnew;
    }
    __syncthreads();
    if (t < 128) {
        float a2 = 0.f;
        for (int k = 0; k < 128; ++k) a2 += gn_s[k] * Wug[k * 128 + t];
        gu[gid * 128 + t] = a2;
    }
}

__global__ __launch_bounds__(512) void k_heads(const float* __restrict__ g,
                                               const float* __restrict__ Wv,
                                               const float* __restrict__ bv,
                                               const float* __restrict__ Was,
                                               const float* __restrict__ bas,
                                               float* __restrict__ dout,
                                               float* __restrict__ aprob,
                                               int* __restrict__ asel,
                                               uint32_t ka0, uint32_t ka1) {
    int gid = threadIdx.x;
    const float* gr = g + (size_t)gid * EMB;
    float v = 0.f;
    float l[4] = {bas[0], bas[1], bas[2], bas[3]};
    for (int k = 0; k < EMB; ++k) {
        float gk = gr[k];
        v += gk * Wv[k];
        float4 w = *reinterpret_cast<const float4*>(Was + k * 4);
        l[0] += gk * w.x; l[1] += gk * w.y; l[2] += gk * w.z; l[3] += gk * w.w;
    }
    v += bv[0];
    const float tiny = 1.17549435e-38f;
    float pert[4];
#pragma unroll
    for (int a = 0; a < 4; ++a) {
        uint32_t bits = draw_bits32(ka0, ka1, (uint32_t)(gid * 4 + a), 2048u);
        float f = bits_to_unit(bits);
        float u = fmaxf(tiny, f + tiny);
        float gum = -logf(-logf(u));
        pert[a] = l[a] + gum;
    }
    int best = 0;
    float bs = pert[0];
#pragma unroll
    for (int a = 1; a < 4; ++a) if (pert[a] > bs) { bs = pert[a]; best = a; }
    float mx = fmaxf(fmaxf(l[0], l[1]), fmaxf(l[2], l[3]));
    float e0 = expf(l[0] - mx), e1 = expf(l[1] - mx), e2 = expf(l[2] - mx), e3 = expf(l[3] - mx);
    float sum = e0 + e1 + e2 + e3;
    float pa = (best == 0 ? e0 : best == 1 ? e1 : best == 2 ? e2 : e3) / sum;
    dout[gid] = (float)best;
    dout[1024 + gid] = v;
    aprob[gid] = pa;
    asel[gid] = best;
}

__global__ __launch_bounds__(128) void k_node(const float* __restrict__ x,
                                              const float* __restrict__ Wns,
                                              const float* __restrict__ bns,
                                              const int* __restrict__ asel,
                                              const float* __restrict__ aprob,
                                              float* __restrict__ dout,
                                              uint32_t kn0, uint32_t kn1) {
    __shared__ float xt[128][129];
    __shared__ float red[128];
    __shared__ float si[128];
    __shared__ int ii[128];
    int gid = blockIdx.x, n = threadIdx.x;
    const float* xb = x + (size_t)gid * NPG * EMB;
    for (int r = 0; r < 128; ++r) xt[r][n] = xb[(size_t)r * EMB + n];
    __syncthreads();
    int a = asel[gid];
    float na = bns[a];
    for (int k = 0; k < EMB; ++k) na += xt[n][k] * Wns[k * 4 + a];
    red[n] = na;
    __syncthreads();
    for (int off = 64; off; off >>= 1) {
        if (n < off) red[n] = fmaxf(red[n], red[n + off]);
        __syncthreads();
    }
    float mx = red[0];
    __syncthreads();
    float e = expf(na - mx);
    red[n] = e;
    __syncthreads();
    for (int off = 64; off; off >>= 1) {
        if (n < off) red[n] += red[n + off];
        __syncthreads();
    }
    float denom = red[0];
    __syncthreads();
    float ns = e / denom;
    uint32_t t = (uint32_t)(gid * 128 + n);
    uint32_t bits = draw_bits32(kn0, kn1, t, 65536u);
    float f = bits_to_unit(bits);
    float u = fmaxf(1e-20f, f + 1e-20f);
    float gum = -logf(-logf(u));
    float score = logf(ns + 1e-20f) + gum;
    si[n] = score;
    ii[n] = n;
    __syncthreads();
    for (int off = 64; off; off >>= 1) {
        if (n < off) {
            float s2 = si[n + off]; int i2 = ii[n + off];
            if (s2 > si[n] || (s2 == si[n] && i2 < ii[n])) { si[n] = s2; ii[n] = i2; }
        }
        __syncthreads();
    }
    int nsel = ii[0];
    __syncthreads();
    si[n] = ns;
    __syncthreads();
    if (n == 0) {
        dout[512 + gid] = (float)nsel;
        dout[1536 + gid] = aprob[gid] * si[nsel];
    }
}

extern "C" void kernel_launch(void* const* d_in, const int* in_sizes, int n_in,
                              void* d_out, int out_size, void* d_ws, size_t ws_size,
                              hipStream_t stream) {
    const float* nf  = (const float*)d_in[0];
    const float* ea  = (const float*)d_in[1];
    const int*   ei  = (const int*)d_in[2];
    const float* We  = (const float*)d_in[3];
    const float* be  = (const float*)d_in[4];
    const float* Ws  = (const float*)d_in[5];
    const float* Wd  = (const float*)d_in[6];
    const float* Wme = (const float*)d_in[7];
    const float* bm  = (const float*)d_in[8];
    const float* Wux = (const float*)d_in[9];
    const float* Wum = (const float*)d_in[10];
    const float* Wug = (const float*)d_in[11];
    const float* bu  = (const float*)d_in[12];
    const float* Wgg = (const float*)d_in[13];
    const float* Wgp = (const float*)d_in[14];
    const float* bg  = (const float*)d_in[15];
    const float* Wns = (const float*)d_in[16];
    const float* bns = (const float*)d_in[17];
    const float* Was = (const float*)d_in[18];
    const float* bas = (const float*)d_in[19];
    const float* Wv  = (const float*)d_in[20];
    const float* bv  = (const float*)d_in[21];
    (void)in_sizes; (void)n_in; (void)out_size; (void)ws_size;

    char* p = (char*)d_ws;
    auto alloc = [&](size_t bytes) {
        void* r = (void*)p;
        p += (bytes + 255) & ~(size_t)255;
        return r;
    };
    const size_t NB = sizeof(float) * (size_t)N_NODES * EMB;
    float* x    = (float*)alloc(NB);
    float* xs   = (float*)alloc(NB);
    float* xd   = (float*)alloc(NB);
    float* agg  = (float*)alloc(NB);
    ushort* Wp  = (ushort*)alloc(sizeof(ushort) * 4 * 3 * 128 * 128);
    float* g    = (float*)alloc(sizeof(float) * G_GRAPHS * EMB);
    float* gu   = (float*)alloc(sizeof(float) * G_GRAPHS * EMB);
    float* aprob = (float*)alloc(sizeof(float) * G_GRAPHS);
    int*   asel  = (int*)alloc(sizeof(int) * G_GRAPHS);
    int*   deg    = (int*)alloc(sizeof(int) * N_NODES);
    int*   indptr = (int*)alloc(sizeof(int) * (N_NODES + 1));
    int*   cursor = (int*)alloc(sizeof(int) * N_NODES);
    int*   eid    = (int*)alloc(sizeof(int) * N_EDGES);
    int*   srcs   = (int*)alloc(sizeof(int) * N_EDGES);
    float2* att   = (float2*)alloc(sizeof(float2) * N_EDGES);

    // ---- CSR by dst (deterministic via wave-bitonic eid sort) ----
    hipMemsetAsync(deg, 0, sizeof(int) * N_NODES, stream);
    k_deg<<<N_EDGES / 256, 256, 0, stream>>>(ei, deg);
    k_scan<<<1, 1024, 0, stream>>>(deg, indptr, cursor);
    k_scatter<<<N_EDGES / 256, 256, 0, stream>>>(ei, cursor, eid);
    k_sortw<<<N_NODES / 4, 256, 0, stream>>>(indptr, eid);
    k_gather<<<N_EDGES / 256, 256, 0, stream>>>(eid, ei, ea, srcs, att);

    // ---- weight split + embed + init global ----
    k_split_w<<<(4 * 128 * 128) / 256, 256, 0, stream>>>(Ws, Wd, Wux, Wum, Wp);
    k_embed<<<(N_NODES * EMB) / 256, 256, 0, stream>>>(nf, We, be, x);
    k_pool0<<<G_GRAPHS, 128, 0, stream>>>(x, g, gu, Wug);

    // ---- message-passing iterations ----
    for (int it = 0; it < ITERS; ++it) {
        k_gemmP<<<N_NODES / 128, 256, 0, stream>>>(x, Wp, bm, xs, xd);
        k_edge<<<dim3(N_NODES / 4), dim3(64, 4), 0, stream>>>(xs, xd, agg, indptr, srcs, att, Wme);
        k_upd<<<N_NODES / 128, 256, 0, stream>>>(x, agg, Wp, bu, x, g, gu, Wgg, Wgp, bg, Wug);
    }

    // ---- heads + sampling ----
    uint32_t ka0, ka1, kn0, kn1;
#if RNG_MODE == 0
    tf2x32(0u, 42u, 0u, 0u, ka0, ka1);
    tf2x32(0u, 42u, 0u, 1u, kn0, kn1);
#else
    {
        uint32_t a0, b0, a1, b1;
        tf2x32(0u, 42u, 0u, 2u, a0, b0);
        tf2x32(0u, 42u, 1u, 3u, a1, b1);
        ka0 = a0; ka1 = a1; kn0 = b0; kn1 = b1;
    }
#endif
    k_heads<<<1, 512, 0, stream>>>(g, Wv, bv, Was, bas, (float*)d_out, aprob, asel, ka0, ka1);
    k_node<<<G_GRAPHS, 128, 0, stream>>>(x, Wns, bns, asel, aprob, (float*)d_out, kn0, kn1);
}

// Round 5
// 1583.680 us; speedup vs baseline: 1.1730x; 1.1730x over previous
//
#include <hip/hip_runtime.h>
#include <stdint.h>

#define N_NODES 65536
#define N_EDGES (N_NODES * 16)
#define EMB 128
#define G_GRAPHS 512
#define NPG 128
#define ITERS 8

#define RNG_MODE 0

typedef __attribute__((ext_vector_type(8))) short short8v;
typedef __attribute__((ext_vector_type(4))) float f32x4;

#define MFMA16(a, b, c) __builtin_amdgcn_mfma_f32_16x16x32_bf16((a), (b), (c), 0, 0, 0)

__host__ __device__ __forceinline__ uint32_t rotl32(uint32_t v, int r) {
    return (v << r) | (v >> (32 - r));
}

// JAX threefry2x32, 20 rounds, exact key schedule
__host__ __device__ __forceinline__ void tf2x32(uint32_t k0, uint32_t k1,
                                                uint32_t x0, uint32_t x1,
                                                uint32_t& o0, uint32_t& o1) {
    uint32_t ks2 = k0 ^ k1 ^ 0x1BD11BDAu;
    x0 += k0; x1 += k1;
#define TF_R(r) { x0 += x1; x1 = rotl32(x1, (r)); x1 ^= x0; }
    TF_R(13) TF_R(15) TF_R(26) TF_R(6)
    x0 += k1;  x1 += ks2 + 1u;
    TF_R(17) TF_R(29) TF_R(16) TF_R(24)
    x0 += ks2; x1 += k0 + 2u;
    TF_R(13) TF_R(15) TF_R(26) TF_R(6)
    x0 += k0;  x1 += k1 + 3u;
    TF_R(17) TF_R(29) TF_R(16) TF_R(24)
    x0 += k1;  x1 += ks2 + 4u;
    TF_R(13) TF_R(15) TF_R(26) TF_R(6)
    x0 += ks2; x1 += k0 + 5u;
#undef TF_R
    o0 = x0; o1 = x1;
}

__device__ __forceinline__ uint32_t draw_bits32(uint32_t k0, uint32_t k1,
                                                uint32_t idx, uint32_t total) {
#if RNG_MODE == 0
    uint32_t a, b;
    tf2x32(k0, k1, 0u, idx, a, b);
    return a ^ b;
#else
    uint32_t half = total >> 1;
    uint32_t a, b;
    if (idx < half) { tf2x32(k0, k1, idx, idx + half, a, b); return a; }
    else            { tf2x32(k0, k1, idx - half, idx, a, b); return b; }
#endif
}

__device__ __forceinline__ float bits_to_unit(uint32_t bits) {
    return __uint_as_float((bits >> 9) | 0x3f800000u) - 1.0f;
}

__device__ __forceinline__ float lrelu(float v) { return v >= 0.0f ? v : 0.01f * v; }

// fp32 -> bf16 RNE
__device__ __forceinline__ ushort f2bf(float f) {
    uint32_t u = __float_as_uint(f);
    u = u + 0x7fffu + ((u >> 16) & 1u);
    return (ushort)(u >> 16);
}
__device__ __forceinline__ float bf2f(ushort h) {
    return __uint_as_float(((uint32_t)h) << 16);
}
__device__ __forceinline__ void split3(float a, ushort& h, ushort& m, ushort& l) {
    h = f2bf(a); float r = a - bf2f(h);
    m = f2bf(r); r = r - bf2f(m);
    l = f2bf(r);
}

// ---------------- CSR build ----------------

__global__ void k_deg(const int* __restrict__ ei, int* __restrict__ deg) {
    int e = blockIdx.x * 256 + threadIdx.x;
    if (e < N_EDGES) atomicAdd(&deg[ei[N_EDGES + e]], 1);
}

__global__ __launch_bounds__(1024) void k_scan(const int* __restrict__ deg,
                                               int* __restrict__ indptr,
                                               int* __restrict__ cursor) {
    __shared__ int part[1024];
    int t = threadIdx.x;
    int base = t * 64;
    int s = 0;
    for (int i = 0; i < 64; ++i) s += deg[base + i];
    part[t] = s;
    __syncthreads();
    for (int off = 1; off < 1024; off <<= 1) {
        int v = (t >= off) ? part[t - off] : 0;
        __syncthreads();
        part[t] += v;
        __syncthreads();
    }
    int run = (t == 0) ? 0 : part[t - 1];
    for (int i = 0; i < 64; ++i) {
        int idx = base + i;
        indptr[idx] = run;
        cursor[idx] = run;
        run += deg[idx];
    }
    if (t == 1023) indptr[N_NODES] = run;
}

__global__ void k_scatter(const int* __restrict__ ei, int* __restrict__ cursor,
                          int* __restrict__ eid) {
    int e = blockIdx.x * 256 + threadIdx.x;
    if (e < N_EDGES) {
        int d = ei[N_EDGES + e];
        int pos = atomicAdd(&cursor[d], 1);
        eid[pos] = e;
    }
}

// wave-parallel bitonic sort of each node's edge-id segment (ascending)
__global__ __launch_bounds__(256) void k_sortw(const int* __restrict__ indptr,
                                               int* __restrict__ eid) {
    int node = blockIdx.x * 4 + (threadIdx.x >> 6);
    int lane = threadIdx.x & 63;
    int b = indptr[node], e = indptr[node + 1];
    int deg = e - b;
    if (deg <= 1) return;
    if (deg > 64) {
        if (lane == 0) {
            for (int p = b + 1; p < e; ++p) {
                int v = eid[p];
                int q = p - 1;
                while (q >= b && eid[q] > v) { eid[q + 1] = eid[q]; --q; }
                eid[q + 1] = v;
            }
        }
        return;
    }
    int v = (lane < deg) ? eid[b + lane] : 0x7fffffff;
#pragma unroll
    for (int k = 2; k <= 64; k <<= 1) {
#pragma unroll
        for (int j = k >> 1; j > 0; j >>= 1) {
            int other = __shfl_xor(v, j);
            int partner = lane ^ j;
            bool up = ((lane & k) == 0);
            bool keepMin = ((lane < partner) == up);
            int mn = min(v, other), mx = max(v, other);
            v = keepMin ? mn : mx;
        }
    }
    if (lane < deg) eid[b + lane] = v;
}

__global__ void k_gather(const int* __restrict__ eid, const int* __restrict__ ei,
                         const float* __restrict__ ea, int* __restrict__ srcs,
                         float2* __restrict__ att) {
    int p = blockIdx.x * 256 + threadIdx.x;
    if (p >= N_EDGES) return;
    int e = eid[p];
    srcs[p] = ei[e];
    att[p] = *reinterpret_cast<const float2*>(ea + 2 * (size_t)e);
}

// ---------------- weight pre-split ----------------
// Wp layout (bf16/ushort): idx = (((mat*4 + kb)*3 + lev)*128 + col)*32 + kk
// mats: 0=Ws, 1=Wd, 2=Wux, 3=Wum
__global__ void k_split_w(const float* __restrict__ W0, const float* __restrict__ W1,
                          const float* __restrict__ W2, const float* __restrict__ W3,
                          ushort* __restrict__ Wp) {
    int tid = blockIdx.x * 256 + threadIdx.x;
    int mat = tid >> 14;
    int rem = tid & 16383;
    int k = rem >> 7, col = rem & 127;
    const float* W = (mat == 0) ? W0 : (mat == 1) ? W1 : (mat == 2) ? W2 : W3;
    float w = W[k * 128 + col];
    ushort h, m, l;
    split3(w, h, m, l);
    int kb = k >> 5, kk = k & 31;
    size_t base = (((size_t)(mat * 4 + kb) * 3) * 128 + col) * 32 + kk;
    Wp[base] = h;
    Wp[base + 4096] = m;
    Wp[base + 8192] = l;
}

// ---------------- network ----------------

__global__ void k_embed(const float* __restrict__ nf, const float* __restrict__ We,
                        const float* __restrict__ be, float* __restrict__ x) {
    int idx = blockIdx.x * 256 + threadIdx.x;
    int n = idx >> 7, j = idx & 127;
    float acc = be[j];
#pragma unroll
    for (int f = 0; f < 5; ++f) acc += nf[n * 5 + f] * We[f * EMB + j];
    x[idx] = lrelu(acc);
}

__global__ __launch_bounds__(128) void k_pool0(const float* __restrict__ x,
                                               float* __restrict__ g, float* __restrict__ gu,
                                               const float* __restrict__ Wug) {
    __shared__ float pl[128];
    int gid = blockIdx.x, j = threadIdx.x;
    const float* xb = x + (size_t)gid * NPG * EMB;
    float s = 0.f;
    for (int n = 0; n < NPG; ++n) s += xb[n * EMB + j];
    s *= (1.0f / NPG);
    g[gid * EMB + j] = s;
    pl[j] = s;
    __syncthreads();
    float acc = 0.f;
    for (int k = 0; k < EMB; ++k) acc += pl[k] * Wug[k * EMB + j];
    gu[gid * EMB + j] = acc;
}

// MFMA split-bf16 projections: xs = x@Ws, xd = x@Wd + bm  (used once, for iteration 0)
__global__ __launch_bounds__(256, 2) void k_gemmP(const float* __restrict__ x,
                                                  const ushort* __restrict__ Wp,
                                                  const float* __restrict__ bm,
                                                  float* __restrict__ xs,
                                                  float* __restrict__ xd) {
    int wid = threadIdx.x >> 6, lane = threadIdx.x & 63;
    int rowq = lane & 15, half = lane >> 4;
    int wrow = blockIdx.x * 128 + wid * 32;
    int laneoff = rowq * 32 + half * 8;

    for (int mat = 0; mat < 2; ++mat) {
        f32x4 acc[2][8];
#pragma unroll
        for (int rt = 0; rt < 2; ++rt)
#pragma unroll
            for (int ct = 0; ct < 8; ++ct) acc[rt][ct] = (f32x4){0.f, 0.f, 0.f, 0.f};
        for (int kb = 0; kb < 4; ++kb) {
            short8v Ah[2], Am[2], Al[2];
#pragma unroll
            for (int rt = 0; rt < 2; ++rt) {
                const float* ap = x + (size_t)(wrow + rt * 16 + rowq) * 128 + kb * 32 + half * 8;
                float4 a0 = *reinterpret_cast<const float4*>(ap);
                float4 a1 = *reinterpret_cast<const float4*>(ap + 4);
                float av[8] = {a0.x, a0.y, a0.z, a0.w, a1.x, a1.y, a1.z, a1.w};
#pragma unroll
                for (int j = 0; j < 8; ++j) {
                    ushort h, m, l;
                    split3(av[j], h, m, l);
                    Ah[rt][j] = (short)h; Am[rt][j] = (short)m; Al[rt][j] = (short)l;
                }
            }
            const ushort* b0 = Wp + (size_t)(mat * 4 + kb) * 3 * 4096 + laneoff;
#pragma unroll
            for (int ct = 0; ct < 8; ++ct) {
                short8v Bh = *reinterpret_cast<const short8v*>(b0 + ct * 512);
                short8v Bm = *reinterpret_cast<const short8v*>(b0 + 4096 + ct * 512);
                short8v Bl = *reinterpret_cast<const short8v*>(b0 + 8192 + ct * 512);
#pragma unroll
                for (int rt = 0; rt < 2; ++rt) {
                    acc[rt][ct] = MFMA16(Ah[rt], Bh, acc[rt][ct]);
                    acc[rt][ct] = MFMA16(Ah[rt], Bm, acc[rt][ct]);
                    acc[rt][ct] = MFMA16(Am[rt], Bh, acc[rt][ct]);
                    acc[rt][ct] = MFMA16(Ah[rt], Bl, acc[rt][ct]);
                    acc[rt][ct] = MFMA16(Al[rt], Bh, acc[rt][ct]);
                    acc[rt][ct] = MFMA16(Am[rt], Bm, acc[rt][ct]);
                }
            }
        }
        float* out = (mat == 0) ? xs : xd;
#pragma unroll
        for (int ct = 0; ct < 8; ++ct) {
            int col = ct * 16 + rowq;
            float badd = (mat == 1) ? bm[col] : 0.f;
#pragma unroll
            for (int rt = 0; rt < 2; ++rt) {
#pragma unroll
                for (int j = 0; j < 4; ++j) {
                    int row = wrow + rt * 16 + half * 4 + j;
                    out[(size_t)row * 128 + col] = acc[rt][ct][j] + badd;
                }
            }
        }
    }
}

// per-dst aggregation, float2/lane, 8-deep batched loads (R3-proven version)
__global__ __launch_bounds__(256) void k_edge(const float* __restrict__ xs,
                                              const float* __restrict__ xd,
                                              float* __restrict__ agg,
                                              const int* __restrict__ indptr,
                                              const int* __restrict__ srcs,
                                              const float2* __restrict__ att,
                                              const float* __restrict__ Wme) {
    int node = blockIdx.x * 4 + threadIdx.y;
    int j = threadIdx.x;
    const float2* xs2 = reinterpret_cast<const float2*>(xs);
    float2 w0 = reinterpret_cast<const float2*>(Wme)[j];
    float2 w1 = reinterpret_cast<const float2*>(Wme + EMB)[j];
    float2 bv = reinterpret_cast<const float2*>(xd)[node * 64 + j];
    float bx = bv.x, by = bv.y;
    int b = indptr[node], e = indptr[node + 1];
    float ax = 0.f, ay = 0.f;
    int p = b;
    for (; p + 8 <= e; p += 8) {
        int s[8]; float2 a[8]; float2 v[8];
#pragma unroll
        for (int i = 0; i < 8; ++i) s[i] = srcs[p + i];
#pragma unroll
        for (int i = 0; i < 8; ++i) a[i] = att[p + i];
#pragma unroll
        for (int i = 0; i < 8; ++i) v[i] = xs2[s[i] * 64 + j];
#pragma unroll
        for (int i = 0; i < 8; ++i) {
            ax += lrelu(v[i].x + bx + a[i].x * w0.x + a[i].y * w1.x);
            ay += lrelu(v[i].y + by + a[i].x * w0.y + a[i].y * w1.y);
        }
    }
    if (p + 4 <= e) {
        int s[4]; float2 a[4]; float2 v[4];
#pragma unroll
        for (int i = 0; i < 4; ++i) s[i] = srcs[p + i];
#pragma unroll
        for (int i = 0; i < 4; ++i) a[i] = att[p + i];
#pragma unroll
        for (int i = 0; i < 4; ++i) v[i] = xs2[s[i] * 64 + j];
#pragma unroll
        for (int i = 0; i < 4; ++i) {
            ax += lrelu(v[i].x + bx + a[i].x * w0.x + a[i].y * w1.x);
            ay += lrelu(v[i].y + by + a[i].x * w0.y + a[i].y * w1.y);
        }
        p += 4;
    }
    for (; p < e; ++p) {
        int s = srcs[p];
        float2 a = att[p];
        float2 v = xs2[s * 64 + j];
        ax += lrelu(v.x + bx + a.x * w0.x + a.y * w1.x);
        ay += lrelu(v.y + by + a.x * w0.y + a.y * w1.y);
    }
    reinterpret_cast<float2*>(agg)[node * 64 + j] = make_float2(ax, ay);
}

// Fused: x = lrelu(x@Wux + agg@Wum + gu + bu); pooled/g/gu update;
// then (do_proj) xs = x@Ws, xd = x@Wd + bm for the NEXT iteration,
// reading the just-written x rows (block == graph => same-XCD L2 hits).
__global__ __launch_bounds__(256, 2) void k_upd(const float* __restrict__ x_in,
                                                const float* __restrict__ agg,
                                                const ushort* __restrict__ Wp,
                                                const float* __restrict__ bu,
                                                float* __restrict__ x,
                                                float* __restrict__ g,
                                                float* __restrict__ gu,
                                                const float* __restrict__ Wgg,
                                                const float* __restrict__ Wgp,
                                                const float* __restrict__ bg,
                                                const float* __restrict__ Wug,
                                                const float* __restrict__ bm,
                                                float* __restrict__ xs,
                                                float* __restrict__ xd,
                                                int do_proj) {
    __shared__ float pl[4][128];
    __shared__ float pooled_s[128];
    __shared__ float go_s[128];
    __shared__ float gn_s[128];
    int wid = threadIdx.x >> 6, lane = threadIdx.x & 63;
    int rowq = lane & 15, half = lane >> 4;
    int gid = blockIdx.x;
    int wrow = gid * 128 + wid * 32;
    int laneoff = rowq * 32 + half * 8;

    {
        f32x4 acc[2][8];
#pragma unroll
        for (int rt = 0; rt < 2; ++rt)
#pragma unroll
            for (int ct = 0; ct < 8; ++ct) acc[rt][ct] = (f32x4){0.f, 0.f, 0.f, 0.f};

        for (int srci = 0; srci < 2; ++srci) {
            const float* A = (srci == 0) ? x_in : agg;
            int mat = 2 + srci;
            for (int kb = 0; kb < 4; ++kb) {
                short8v Ah[2], Am[2], Al[2];
#pragma unroll
                for (int rt = 0; rt < 2; ++rt) {
                    const float* ap = A + (size_t)(wrow + rt * 16 + rowq) * 128 + kb * 32 + half * 8;
                    float4 a0 = *reinterpret_cast<const float4*>(ap);
                    float4 a1 = *reinterpret_cast<const float4*>(ap + 4);
                    float av[8] = {a0.x, a0.y, a0.z, a0.w, a1.x, a1.y, a1.z, a1.w};
#pragma unroll
                    for (int j = 0; j < 8; ++j) {
                        ushort h, m, l;
                        split3(av[j], h, m, l);
                        Ah[rt][j] = (short)h; Am[rt][j] = (short)m; Al[rt][j] = (short)l;
                    }
                }
                const ushort* b0 = Wp + (size_t)(mat * 4 + kb) * 3 * 4096 + laneoff;
#pragma unroll
                for (int ct = 0; ct < 8; ++ct) {
                    short8v Bh = *reinterpret_cast<const short8v*>(b0 + ct * 512);
                    short8v Bm = *reinterpret_cast<const short8v*>(b0 + 4096 + ct * 512);
                    short8v Bl = *reinterpret_cast<const short8v*>(b0 + 8192 + ct * 512);
#pragma unroll
                    for (int rt = 0; rt < 2; ++rt) {
                        acc[rt][ct] = MFMA16(Ah[rt], Bh, acc[rt][ct]);
                        acc[rt][ct] = MFMA16(Ah[rt], Bm, acc[rt][ct]);
                        acc[rt][ct] = MFMA16(Am[rt], Bh, acc[rt][ct]);
                        acc[rt][ct] = MFMA16(Ah[rt], Bl, acc[rt][ct]);
                        acc[rt][ct] = MFMA16(Al[rt], Bh, acc[rt][ct]);
                        acc[rt][ct] = MFMA16(Am[rt], Bm, acc[rt][ct]);
                    }
                }
            }
        }

#pragma unroll
        for (int ct = 0; ct < 8; ++ct) {
            int col = ct * 16 + rowq;
            float guv = gu[gid * 128 + col];
            float buv = bu[col];
            float csum = 0.f;
#pragma unroll
            for (int rt = 0; rt < 2; ++rt) {
#pragma unroll
                for (int j = 0; j < 4; ++j) {
                    int row = wrow + rt * 16 + half * 4 + j;
                    float o = lrelu(acc[rt][ct][j] + guv + buv);
                    x[(size_t)row * 128 + col] = o;
                    csum += o;
                }
            }
            csum += __shfl_down(csum, 32);
            csum += __shfl_down(csum, 16);
            if (half == 0) pl[wid][col] = csum;
        }
    }
    __syncthreads();   // x stores done + pl ready
    int t = threadIdx.x;
    if (t < 128) {
        pooled_s[t] = (pl[0][t] + pl[1][t] + pl[2][t] + pl[3][t]) * (1.0f / NPG);
        go_s[t] = g[gid * 128 + t];
    }
    __syncthreads();
    if (t < 128) {
        float accg = bg[t];
        for (int k = 0; k < 128; ++k) accg += go_s[k] * Wgg[k * 128 + t];
        for (int k = 0; k < 128; ++k) accg += pooled_s[k] * Wgp[k * 128 + t];
        float gnew = lrelu(accg);
        g[gid * 128 + t] = gnew;
        gn_s[t] = gnew;
    }
    __syncthreads();
    if (t < 128) {
        float a2 = 0.f;
        for (int k = 0; k < 128; ++k) a2 += gn_s[k] * Wug[k * 128 + t];
        gu[gid * 128 + t] = a2;
    }

    // ---- phase 2: next-iteration projections from just-written x (L2-local) ----
    if (!do_proj) return;
    for (int mat = 0; mat < 2; ++mat) {
        f32x4 acc[2][8];
#pragma unroll
        for (int rt = 0; rt < 2; ++rt)
#pragma unroll
            for (int ct = 0; ct < 8; ++ct) acc[rt][ct] = (f32x4){0.f, 0.f, 0.f, 0.f};
        for (int kb = 0; kb < 4; ++kb) {
            short8v Ah[2], Am[2], Al[2];
#pragma unroll
            for (int rt = 0; rt < 2; ++rt) {
                const float* ap = x + (size_t)(wrow + rt * 16 + rowq) * 128 + kb * 32 + half * 8;
                float4 a0 = *reinterpret_cast<const float4*>(ap);
                float4 a1 = *reinterpret_cast<const float4*>(ap + 4);
                float av[8] = {a0.x, a0.y, a0.z, a0.w, a1.x, a1.y, a1.z, a1.w};
#pragma unroll
                for (int j = 0; j < 8; ++j) {
                    ushort h, m, l;
                    split3(av[j], h, m, l);
                    Ah[rt][j] = (short)h; Am[rt][j] = (short)m; Al[rt][j] = (short)l;
                }
            }
            const ushort* b0 = Wp + (size_t)(mat * 4 + kb) * 3 * 4096 + laneoff;
#pragma unroll
            for (int ct = 0; ct < 8; ++ct) {
                short8v Bh = *reinterpret_cast<const short8v*>(b0 + ct * 512);
                short8v Bm = *reinterpret_cast<const short8v*>(b0 + 4096 + ct * 512);
                short8v Bl = *reinterpret_cast<const short8v*>(b0 + 8192 + ct * 512);
#pragma unroll
                for (int rt = 0; rt < 2; ++rt) {
                    acc[rt][ct] = MFMA16(Ah[rt], Bh, acc[rt][ct]);
                    acc[rt][ct] = MFMA16(Ah[rt], Bm, acc[rt][ct]);
                    acc[rt][ct] = MFMA16(Am[rt], Bh, acc[rt][ct]);
                    acc[rt][ct] = MFMA16(Ah[rt], Bl, acc[rt][ct]);
                    acc[rt][ct] = MFMA16(Al[rt], Bh, acc[rt][ct]);
                    acc[rt][ct] = MFMA16(Am[rt], Bm, acc[rt][ct]);
                }
            }
        }
        float* out = (mat == 0) ? xs : xd;
#pragma unroll
        for (int ct = 0; ct < 8; ++ct) {
            int col = ct * 16 + rowq;
            float badd = (mat == 1) ? bm[col] : 0.f;
#pragma unroll
            for (int rt = 0; rt < 2; ++rt) {
#pragma unroll
                for (int j = 0; j < 4; ++j) {
                    int row = wrow + rt * 16 + half * 4 + j;
                    out[(size_t)row * 128 + col] = acc[rt][ct][j] + badd;
                }
            }
        }
    }
}

__global__ __launch_bounds__(512) void k_heads(const float* __restrict__ g,
                                               const float* __restrict__ Wv,
                                               const float* __restrict__ bv,
                                               const float* __restrict__ Was,
                                               const float* __restrict__ bas,
                                               float* __restrict__ dout,
                                               float* __restrict__ aprob,
                                               int* __restrict__ asel,
                                               uint32_t ka0, uint32_t ka1) {
    int gid = threadIdx.x;
    const float* gr = g + (size_t)gid * EMB;
    float v = 0.f;
    float l[4] = {bas[0], bas[1], bas[2], bas[3]};
    for (int k = 0; k < EMB; ++k) {
        float gk = gr[k];
        v += gk * Wv[k];
        float4 w = *reinterpret_cast<const float4*>(Was + k * 4);
        l[0] += gk * w.x; l[1] += gk * w.y; l[2] += gk * w.z; l[3] += gk * w.w;
    }
    v += bv[0];
    const float tiny = 1.17549435e-38f;
    float pert[4];
#pragma unroll
    for (int a = 0; a < 4; ++a) {
        uint32_t bits = draw_bits32(ka0, ka1, (uint32_t)(gid * 4 + a), 2048u);
        float f = bits_to_unit(bits);
        float u = fmaxf(tiny, f + tiny);
        float gum = -logf(-logf(u));
        pert[a] = l[a] + gum;
    }
    int best = 0;
    float bs = pert[0];
#pragma unroll
    for (int a = 1; a < 4; ++a) if (pert[a] > bs) { bs = pert[a]; best = a; }
    float mx = fmaxf(fmaxf(l[0], l[1]), fmaxf(l[2], l[3]));
    float e0 = expf(l[0] - mx), e1 = expf(l[1] - mx), e2 = expf(l[2] - mx), e3 = expf(l[3] - mx);
    float sum = e0 + e1 + e2 + e3;
    float pa = (best == 0 ? e0 : best == 1 ? e1 : best == 2 ? e2 : e3) / sum;
    dout[gid] = (float)best;
    dout[1024 + gid] = v;
    aprob[gid] = pa;
    asel[gid] = best;
}

__global__ __launch_bounds__(128) void k_node(const float* __restrict__ x,
                                              const float* __restrict__ Wns,
                                              const float* __restrict__ bns,
                                              const int* __restrict__ asel,
                                              const float* __restrict__ aprob,
                                              float* __restrict__ dout,
                                              uint32_t kn0, uint32_t kn1) {
    __shared__ float xt[128][129];
    __shared__ float red[128];
    __shared__ float si[128];
    __shared__ int ii[128];
    int gid = blockIdx.x, n = threadIdx.x;
    const float* xb = x + (size_t)gid * NPG * EMB;
    for (int r = 0; r < 128; ++r) xt[r][n] = xb[(size_t)r * EMB + n];
    __syncthreads();
    int a = asel[gid];
    float na = bns[a];
    for (int k = 0; k < EMB; ++k) na += xt[n][k] * Wns[k * 4 + a];
    red[n] = na;
    __syncthreads();
    for (int off = 64; off; off >>= 1) {
        if (n < off) red[n] = fmaxf(red[n], red[n + off]);
        __syncthreads();
    }
    float mx = red[0];
    __syncthreads();
    float e = expf(na - mx);
    red[n] = e;
    __syncthreads();
    for (int off = 64; off; off >>= 1) {
        if (n < off) red[n] += red[n + off];
        __syncthreads();
    }
    float denom = red[0];
    __syncthreads();
    float ns = e / denom;
    uint32_t t = (uint32_t)(gid * 128 + n);
    uint32_t bits = draw_bits32(kn0, kn1, t, 65536u);
    float f = bits_to_unit(bits);
    float u = fmaxf(1e-20f, f + 1e-20f);
    float gum = -logf(-logf(u));
    float score = logf(ns + 1e-20f) + gum;
    si[n] = score;
    ii[n] = n;
    __syncthreads();
    for (int off = 64; off; off >>= 1) {
        if (n < off) {
            float s2 = si[n + off]; int i2 = ii[n + off];
            if (s2 > si[n] || (s2 == si[n] && i2 < ii[n])) { si[n] = s2; ii[n] = i2; }
        }
        __syncthreads();
    }
    int nsel = ii[0];
    __syncthreads();
    si[n] = ns;
    __syncthreads();
    if (n == 0) {
        dout[512 + gid] = (float)nsel;
        dout[1536 + gid] = aprob[gid] * si[nsel];
    }
}

extern "C" void kernel_launch(void* const* d_in, const int* in_sizes, int n_in,
                              void* d_out, int out_size, void* d_ws, size_t ws_size,
                              hipStream_t stream) {
    const float* nf  = (const float*)d_in[0];
    const float* ea  = (const float*)d_in[1];
    const int*   ei  = (const int*)d_in[2];
    const float* We  = (const float*)d_in[3];
    const float* be  = (const float*)d_in[4];
    const float* Ws  = (const float*)d_in[5];
    const float* Wd  = (const float*)d_in[6];
    const float* Wme = (const float*)d_in[7];
    const float* bm  = (const float*)d_in[8];
    const float* Wux = (const float*)d_in[9];
    const float* Wum = (const float*)d_in[10];
    const float* Wug = (const float*)d_in[11];
    const float* bu  = (const float*)d_in[12];
    const float* Wgg = (const float*)d_in[13];
    const float* Wgp = (const float*)d_in[14];
    const float* bg  = (const float*)d_in[15];
    const float* Wns = (const float*)d_in[16];
    const float* bns = (const float*)d_in[17];
    const float* Was = (const float*)d_in[18];
    const float* bas = (const float*)d_in[19];
    const float* Wv  = (const float*)d_in[20];
    const float* bv  = (const float*)d_in[21];
    (void)in_sizes; (void)n_in; (void)out_size; (void)ws_size;

    char* p = (char*)d_ws;
    auto alloc = [&](size_t bytes) {
        void* r = (void*)p;
        p += (bytes + 255) & ~(size_t)255;
        return r;
    };
    const size_t NB = sizeof(float) * (size_t)N_NODES * EMB;
    float* x    = (float*)alloc(NB);
    float* xs   = (float*)alloc(NB);
    float* xd   = (float*)alloc(NB);
    float* agg  = (float*)alloc(NB);
    ushort* Wp  = (ushort*)alloc(sizeof(ushort) * 4 * 3 * 128 * 128);
    float* g    = (float*)alloc(sizeof(float) * G_GRAPHS * EMB);
    float* gu   = (float*)alloc(sizeof(float) * G_GRAPHS * EMB);
    float* aprob = (float*)alloc(sizeof(float) * G_GRAPHS);
    int*   asel  = (int*)alloc(sizeof(int) * G_GRAPHS);
    int*   deg    = (int*)alloc(sizeof(int) * N_NODES);
    int*   indptr = (int*)alloc(sizeof(int) * (N_NODES + 1));
    int*   cursor = (int*)alloc(sizeof(int) * N_NODES);
    int*   eid    = (int*)alloc(sizeof(int) * N_EDGES);
    int*   srcs   = (int*)alloc(sizeof(int) * N_EDGES);
    float2* att   = (float2*)alloc(sizeof(float2) * N_EDGES);

    // ---- CSR by dst (deterministic via wave-bitonic eid sort) ----
    hipMemsetAsync(deg, 0, sizeof(int) * N_NODES, stream);
    k_deg<<<N_EDGES / 256, 256, 0, stream>>>(ei, deg);
    k_scan<<<1, 1024, 0, stream>>>(deg, indptr, cursor);
    k_scatter<<<N_EDGES / 256, 256, 0, stream>>>(ei, cursor, eid);
    k_sortw<<<N_NODES / 4, 256, 0, stream>>>(indptr, eid);
    k_gather<<<N_EDGES / 256, 256, 0, stream>>>(eid, ei, ea, srcs, att);

    // ---- weight split + embed + init global + initial projections ----
    k_split_w<<<(4 * 128 * 128) / 256, 256, 0, stream>>>(Ws, Wd, Wux, Wum, Wp);
    k_embed<<<(N_NODES * EMB) / 256, 256, 0, stream>>>(nf, We, be, x);
    k_pool0<<<G_GRAPHS, 128, 0, stream>>>(x, g, gu, Wug);
    k_gemmP<<<N_NODES / 128, 256, 0, stream>>>(x, Wp, bm, xs, xd);

    // ---- message-passing iterations (edge -> fused upd+proj) ----
    for (int it = 0; it < ITERS; ++it) {
        k_edge<<<dim3(N_NODES / 4), dim3(64, 4), 0, stream>>>(xs, xd, agg, indptr, srcs, att, Wme);
        k_upd<<<N_NODES / 128, 256, 0, stream>>>(x, agg, Wp, bu, x, g, gu,
                                                 Wgg, Wgp, bg, Wug, bm, xs, xd,
                                                 (it < ITERS - 1) ? 1 : 0);
    }

    // ---- heads + sampling ----
    uint32_t ka0, ka1, kn0, kn1;
#if RNG_MODE == 0
    tf2x32(0u, 42u, 0u, 0u, ka0, ka1);
    tf2x32(0u, 42u, 0u, 1u, kn0, kn1);
#else
    {
        uint32_t a0, b0, a1, b1;
        tf2x32(0u, 42u, 0u, 2u, a0, b0);
        tf2x32(0u, 42u, 1u, 3u, a1, b1);
        ka0 = a0; ka1 = a1; kn0 = b0; kn1 = b1;
    }
#endif
    k_heads<<<1, 512, 0, stream>>>(g, Wv, bv, Was, bas, (float*)d_out, aprob, asel, ka0, ka1);
    k_node<<<G_GRAPHS, 128, 0, stream>>>(x, Wns, bns, asel, aprob, (float*)d_out, kn0, kn1);
}